// Round 5
// baseline (312.323 us; speedup 1.0000x reference)
//
#include <hip/hip_runtime.h>
#include <hip/hip_bf16.h>

// GIN 2-layer, bf16 feature pipeline + MFMA MLPs.
// CSR fill: XCD-segmented + non-temporal edge-stream loads (protect dirty
// eidx lines in the XCD L2 from streaming-read eviction).

#define NSEG 8

typedef short  bf16x8 __attribute__((ext_vector_type(8)));
typedef float  f32x4  __attribute__((ext_vector_type(4)));

__device__ inline float bf2f(unsigned short u) {
    unsigned int t = ((unsigned int)u) << 16;
    return __builtin_bit_cast(float, t);
}
__device__ inline unsigned short f2bf(float f) {   // round-to-nearest-even
    unsigned int u = __builtin_bit_cast(unsigned int, f);
    u += 0x7fffu + ((u >> 16) & 1u);
    return (unsigned short)(u >> 16);
}

// ---------------- prep: f32 -> bf16 feature convert ----------------
__global__ __launch_bounds__(256) void cvt_bf16_k(
    const float* __restrict__ x, unsigned short* __restrict__ xb, int n8)
{
    int i = blockIdx.x * 256 + threadIdx.x;
    if (i >= n8) return;
    const float4* p = reinterpret_cast<const float4*>(x + (size_t)i * 8);
    float4 a = p[0], b = p[1];
    union { unsigned short us[8]; uint4 v; } o;
    o.us[0] = f2bf(a.x); o.us[1] = f2bf(a.y); o.us[2] = f2bf(a.z); o.us[3] = f2bf(a.w);
    o.us[4] = f2bf(b.x); o.us[5] = f2bf(b.y); o.us[6] = f2bf(b.z); o.us[7] = f2bf(b.w);
    *reinterpret_cast<uint4*>(xb + (size_t)i * 8) = o.v;
}

// ---------------- prep: all 4 weight transposes in one launch ----------------
__global__ __launch_bounds__(256) void wt_prep_all_k(
    const float* __restrict__ W1a, const float* __restrict__ W1b,
    const float* __restrict__ W2a, const float* __restrict__ W2b,
    unsigned short* __restrict__ T1a, unsigned short* __restrict__ T1b,
    unsigned short* __restrict__ T2a, unsigned short* __restrict__ T2b)
{
    int idx = blockIdx.x * 256 + threadIdx.x;
    const float* W; unsigned short* T; int K, N;
    if (idx < 8192)        { W = W1a; T = T1a; K = 64;  N = 128; }
    else if (idx < 24576)  { idx -= 8192;  W = W1b; T = T1b; K = 128; N = 128; }
    else if (idx < 40960)  { idx -= 24576; W = W2a; T = T2a; K = 128; N = 128; }
    else if (idx < 49152)  { idx -= 40960; W = W2b; T = T2b; K = 128; N = 64; }
    else return;
    int n = idx / K, k = idx - n * K;
    T[idx] = f2bf(W[(size_t)k * N + n]);
}

// ---------------- CSR build ----------------
// hist: single pass; cnt (400 KB) atomics are L2-resident, no segmentation needed.
__global__ __launch_bounds__(256) void hist_k(
    const int* __restrict__ dst, int* __restrict__ cnt, int n_edges)
{
    int e = blockIdx.x * 256 + threadIdx.x;
    if (e < n_edges) {
        int d = __builtin_nontemporal_load(&dst[e]);
        atomicAdd(&cnt[d], 1);
    }
}

// fill: seg = blockIdx&7 -> one XCD per node-range segment; nt loads keep the
// streaming src/dst reads from evicting the segment's dirty eidx lines.
__global__ __launch_bounds__(256) void fill_seg_k(
    const int* __restrict__ src, const int* __restrict__ dst,
    int* __restrict__ cur, int* __restrict__ eidx, int n_edges, int segN)
{
    const int seg = blockIdx.x & (NSEG - 1);
    const int chunk = blockIdx.x >> 3;
    const int nchunks = gridDim.x >> 3;
    const int lo = seg * segN, hi = lo + segN;
    for (int e = chunk * 256 + threadIdx.x; e < n_edges; e += nchunks * 256) {
        int d = __builtin_nontemporal_load(&dst[e]);
        if (d >= lo && d < hi) {
            int s = __builtin_nontemporal_load(&src[e]);
            int p = atomicAdd(&cur[d], 1);
            eidx[p] = s;
        }
    }
}

// ---------------- scans (proven) ----------------
__global__ __launch_bounds__(256) void scan_block_k(
    const int* __restrict__ cnt, int* __restrict__ offs, int* __restrict__ bsum, int n)
{
    __shared__ int s[256];
    const int tid = threadIdx.x;
    const int base = blockIdx.x * 2048 + tid * 8;
    int v[8]; int tsum = 0;
    #pragma unroll
    for (int j = 0; j < 8; ++j) {
        int idx = base + j;
        v[j] = (idx < n) ? cnt[idx] : 0;
        tsum += v[j];
    }
    s[tid] = tsum; __syncthreads();
    #pragma unroll
    for (int d = 1; d < 256; d <<= 1) {
        int t = (tid >= d) ? s[tid - d] : 0;
        __syncthreads();
        s[tid] += t;
        __syncthreads();
    }
    int run = s[tid] - tsum;
    #pragma unroll
    for (int j = 0; j < 8; ++j) {
        int idx = base + j;
        if (idx < n) offs[idx] = run;
        run += v[j];
    }
    if (tid == 255) bsum[blockIdx.x] = s[255];
}

__global__ __launch_bounds__(256) void scan_bsum_k(int* __restrict__ bsum, int nb)
{
    __shared__ int s[256];
    const int tid = threadIdx.x;
    int v = (tid < nb) ? bsum[tid] : 0;
    s[tid] = v; __syncthreads();
    #pragma unroll
    for (int d = 1; d < 256; d <<= 1) {
        int t = (tid >= d) ? s[tid - d] : 0;
        __syncthreads();
        s[tid] += t;
        __syncthreads();
    }
    if (tid < nb) bsum[tid] = s[tid] - v;
}

__global__ __launch_bounds__(256) void scan_add_k(
    int* __restrict__ offs, int* __restrict__ cur, const int* __restrict__ bsum, int n)
{
    const int b = bsum[blockIdx.x];
    const int base = blockIdx.x * 2048 + threadIdx.x * 8;
    #pragma unroll
    for (int j = 0; j < 8; ++j) {
        int idx = base + j;
        if (idx < n) { int o = offs[idx] + b; offs[idx] = o; cur[idx] = o; }
    }
}

// ---------------- gather aggregation: A = sum(nbrs) + self, bf16 out ----------
template<int C>
__global__ __launch_bounds__(256) void gather_agg_k(
    const unsigned short* __restrict__ h, const int* __restrict__ offs,
    const int* __restrict__ cnt, const int* __restrict__ eidx,
    unsigned short* __restrict__ A, int n_nodes)
{
    constexpr int TPN = C / 8;
    constexpr int NPB = 256 / TPN;
    const int node = blockIdx.x * NPB + threadIdx.x / TPN;
    const int lane = threadIdx.x % TPN;
    if (node >= n_nodes) return;
    const size_t coff = (size_t)lane * 8;

    float acc[8];
    {   // self contribution (GIN eps=0)
        uint4 v = *reinterpret_cast<const uint4*>(h + (size_t)node * C + coff);
        const unsigned short* u = (const unsigned short*)&v;
        #pragma unroll
        for (int j = 0; j < 8; ++j) acc[j] = bf2f(u[j]);
    }
    const int beg = offs[node], end = beg + cnt[node];
    int p = beg;
    for (; p + 2 <= end; p += 2) {
        int s0 = eidx[p], s1 = eidx[p + 1];
        uint4 v0 = *reinterpret_cast<const uint4*>(h + (size_t)s0 * C + coff);
        uint4 v1 = *reinterpret_cast<const uint4*>(h + (size_t)s1 * C + coff);
        const unsigned short* u0 = (const unsigned short*)&v0;
        const unsigned short* u1 = (const unsigned short*)&v1;
        #pragma unroll
        for (int j = 0; j < 8; ++j) acc[j] += bf2f(u0[j]) + bf2f(u1[j]);
    }
    if (p < end) {
        uint4 v0 = *reinterpret_cast<const uint4*>(h + (size_t)eidx[p] * C + coff);
        const unsigned short* u0 = (const unsigned short*)&v0;
        #pragma unroll
        for (int j = 0; j < 8; ++j) acc[j] += bf2f(u0[j]);
    }
    union { unsigned short us[8]; uint4 v; } o;
    #pragma unroll
    for (int j = 0; j < 8; ++j) o.us[j] = f2bf(acc[j]);
    *reinterpret_cast<uint4*>(A + (size_t)node * C + coff) = o.v;
}

// ---------------- fused 2-GEMM MLP via MFMA bf16 (proven) ----------------
template<int K1, int N2, bool RELU_OUT, bool OUT_BF16>
__global__ __launch_bounds__(256) void mlp_mfma_k(
    const unsigned short* __restrict__ Ain,
    const unsigned short* __restrict__ WTa,
    const float* __restrict__ ba,
    const unsigned short* __restrict__ WTb,
    const float* __restrict__ bb,
    void* __restrict__ outp, int n_nodes)
{
    constexpr int KS1 = K1 / 32;
    constexpr int NT2 = N2 / 16;
    static_assert(64 * N2 * (OUT_BF16 ? 2 : 4) <= 64 * 128 * 2, "out staging fits sMid");

    __shared__ unsigned short sA[64 * K1];
    __shared__ unsigned short sWa[128 * K1];
    __shared__ unsigned short sWb[N2 * 128];
    __shared__ unsigned short sMid[64 * 128];

    const int tid = threadIdx.x;
    const int wave = tid >> 6, lane = tid & 63;
    const int rc = lane & 15;
    const int kg = lane >> 4;
    const int rowBlock = blockIdx.x * 64;

    {   // stage A (guarded rows), swizzled
        constexpr int CPR = K1 / 8;
        #pragma unroll
        for (int f = tid; f < 64 * CPR; f += 256) {
            int r = f / CPR, c = f - r * CPR;
            uint4 v = make_uint4(0u, 0u, 0u, 0u);
            int gr = rowBlock + r;
            if (gr < n_nodes)
                v = *reinterpret_cast<const uint4*>(Ain + (size_t)gr * K1 + c * 8);
            int byte = r * (K1 * 2) + ((c * 16) ^ ((r & 7) << 4));
            *reinterpret_cast<uint4*>((char*)sA + byte) = v;
        }
    }
    {   // stage WTa [128][K1], swizzled
        constexpr int CPR = K1 / 8;
        #pragma unroll
        for (int f = tid; f < 128 * CPR; f += 256) {
            int r = f / CPR, c = f - r * CPR;
            uint4 v = *reinterpret_cast<const uint4*>(WTa + (size_t)r * K1 + c * 8);
            int byte = r * (K1 * 2) + ((c * 16) ^ ((r & 7) << 4));
            *reinterpret_cast<uint4*>((char*)sWa + byte) = v;
        }
    }
    {   // stage WTb [N2][128], swizzled
        #pragma unroll
        for (int f = tid; f < N2 * 16; f += 256) {
            int r = f / 16, c = f - r * 16;
            uint4 v = *reinterpret_cast<const uint4*>(WTb + (size_t)r * 128 + c * 8);
            int byte = r * 256 + ((c * 16) ^ ((r & 7) << 4));
            *reinterpret_cast<uint4*>((char*)sWb + byte) = v;
        }
    }
    __syncthreads();

    // GEMM1: (64 x K1) @ (K1 x 128)
    f32x4 acc1[8];
    #pragma unroll
    for (int n = 0; n < 8; ++n) acc1[n] = (f32x4){0.f, 0.f, 0.f, 0.f};
    bf16x8 af[KS1];
    #pragma unroll
    for (int ks = 0; ks < KS1; ++ks) {
        int r = wave * 16 + rc;
        int byte = r * (K1 * 2) + (((ks * 32 + kg * 8) * 2) ^ ((r & 7) << 4));
        af[ks] = *reinterpret_cast<const bf16x8*>((const char*)sA + byte);
    }
    #pragma unroll
    for (int n = 0; n < 8; ++n) {
        int c = n * 16 + rc;
        #pragma unroll
        for (int ks = 0; ks < KS1; ++ks) {
            int byte = c * (K1 * 2) + (((ks * 32 + kg * 8) * 2) ^ ((c & 7) << 4));
            bf16x8 bfr = *reinterpret_cast<const bf16x8*>((const char*)sWa + byte);
            acc1[n] = __builtin_amdgcn_mfma_f32_16x16x32_bf16(af[ks], bfr, acc1[n], 0, 0, 0);
        }
    }
    // epilogue 1: bias + relu -> sMid bf16 swizzled
    #pragma unroll
    for (int n = 0; n < 8; ++n) {
        int c = n * 16 + rc;
        float bias = ba[c];
        #pragma unroll
        for (int i = 0; i < 4; ++i) {
            int r = wave * 16 + kg * 4 + i;
            float v = fmaxf(acc1[n][i] + bias, 0.f);
            int byte = r * 256 + ((c * 2) ^ ((r & 7) << 4));
            *reinterpret_cast<unsigned short*>((char*)sMid + byte) = f2bf(v);
        }
    }
    __syncthreads();

    // GEMM2: (64 x 128) @ (128 x N2)
    f32x4 acc2[NT2];
    #pragma unroll
    for (int n = 0; n < NT2; ++n) acc2[n] = (f32x4){0.f, 0.f, 0.f, 0.f};
    bf16x8 mf[4];
    #pragma unroll
    for (int ks = 0; ks < 4; ++ks) {
        int r = wave * 16 + rc;
        int byte = r * 256 + (((ks * 32 + kg * 8) * 2) ^ ((r & 7) << 4));
        mf[ks] = *reinterpret_cast<const bf16x8*>((const char*)sMid + byte);
    }
    #pragma unroll
    for (int n = 0; n < NT2; ++n) {
        int c = n * 16 + rc;
        #pragma unroll
        for (int ks = 0; ks < 4; ++ks) {
            int byte = c * 256 + (((ks * 32 + kg * 8) * 2) ^ ((c & 7) << 4));
            bf16x8 bfr = *reinterpret_cast<const bf16x8*>((const char*)sWb + byte);
            acc2[n] = __builtin_amdgcn_mfma_f32_16x16x32_bf16(mf[ks], bfr, acc2[n], 0, 0, 0);
        }
    }
    __syncthreads();

    // epilogue 2: bias [+relu] -> staging -> coalesced store
    if constexpr (OUT_BF16) {
        #pragma unroll
        for (int n = 0; n < NT2; ++n) {
            int c = n * 16 + rc;
            float bias = bb[c];
            #pragma unroll
            for (int i = 0; i < 4; ++i) {
                int r = wave * 16 + kg * 4 + i;
                float v = acc2[n][i] + bias;
                if (RELU_OUT) v = fmaxf(v, 0.f);
                sMid[r * N2 + c] = f2bf(v);
            }
        }
        __syncthreads();
        unsigned short* out = (unsigned short*)outp;
        constexpr int CPR = N2 / 8;
        #pragma unroll
        for (int f = tid; f < 64 * CPR; f += 256) {
            int r = f / CPR, c = f - r * CPR;
            int gr = rowBlock + r;
            if (gr < n_nodes)
                *reinterpret_cast<uint4*>(out + (size_t)gr * N2 + c * 8) =
                    *reinterpret_cast<const uint4*>(sMid + r * N2 + c * 8);
        }
    } else {
        float* sOut = reinterpret_cast<float*>(sMid);
        #pragma unroll
        for (int n = 0; n < NT2; ++n) {
            int c = n * 16 + rc;
            float bias = bb[c];
            #pragma unroll
            for (int i = 0; i < 4; ++i) {
                int r = wave * 16 + kg * 4 + i;
                float v = acc2[n][i] + bias;
                if (RELU_OUT) v = fmaxf(v, 0.f);
                sOut[r * N2 + c] = v;
            }
        }
        __syncthreads();
        float* out = (float*)outp;
        constexpr int CPR = N2 / 4;
        #pragma unroll
        for (int f = tid; f < 64 * CPR; f += 256) {
            int r = f / CPR, c = f - r * CPR;
            int gr = rowBlock + r;
            if (gr < n_nodes)
                *reinterpret_cast<float4*>(out + (size_t)gr * N2 + c * 4) =
                    *reinterpret_cast<const float4*>(sOut + r * N2 + c * 4);
        }
    }
}

extern "C" void kernel_launch(void* const* d_in, const int* in_sizes, int n_in,
                              void* d_out, int out_size, void* d_ws, size_t ws_size,
                              hipStream_t stream)
{
    const float* x   = (const float*)d_in[0];
    const int*   ei  = (const int*)d_in[1];
    const float* W1a = (const float*)d_in[2];
    const float* b1a = (const float*)d_in[3];
    const float* W1b = (const float*)d_in[4];
    const float* b1b = (const float*)d_in[5];
    const float* W2a = (const float*)d_in[6];
    const float* b2a = (const float*)d_in[7];
    const float* W2b = (const float*)d_in[8];
    const float* b2b = (const float*)d_in[9];

    const int n_nodes = in_sizes[0] / 64;
    const int n_edges = in_sizes[1] / 2;
    const int* src = ei;
    const int* dst = ei + n_edges;

    char* ws = (char*)d_ws;
    size_t o = 0;
    auto alloc = [&](size_t bytes) -> char* {
        char* p = ws + o;
        o += (bytes + 255) & ~(size_t)255;
        return p;
    };
    unsigned short* A    = (unsigned short*)alloc((size_t)n_nodes * 128 * 2);
    unsigned short* h    = (unsigned short*)alloc((size_t)n_nodes * 128 * 2);
    unsigned short* xb   = (unsigned short*)alloc((size_t)n_nodes * 64 * 2);
    int* eidx = (int*)alloc((size_t)n_edges * 4);
    int* cnt  = (int*)alloc((size_t)n_nodes * 4);
    int* offs = (int*)alloc((size_t)n_nodes * 4);
    int* cur  = (int*)alloc((size_t)n_nodes * 4);
    int* bsum = (int*)alloc(256 * 4);
    unsigned short* WT1a = (unsigned short*)alloc(64 * 128 * 2);
    unsigned short* WT1b = (unsigned short*)alloc(128 * 128 * 2);
    unsigned short* WT2a = (unsigned short*)alloc(128 * 128 * 2);
    unsigned short* WT2b = (unsigned short*)alloc(128 * 64 * 2);

    const int mlp_grid = (n_nodes + 63) / 64;
    const int segN = (n_nodes + NSEG - 1) / NSEG;
    const int seg_grid = NSEG * 128;
    const int egrid = (n_edges + 255) / 256;

    // ---- prep ----
    cvt_bf16_k<<<(n_nodes * 8 + 255) / 256, 256, 0, stream>>>(x, xb, n_nodes * 8);
    wt_prep_all_k<<<192, 256, 0, stream>>>(W1a, W1b, W2a, W2b, WT1a, WT1b, WT2a, WT2b);

    // ---- CSR build ----
    hipMemsetAsync(cnt, 0, (size_t)n_nodes * sizeof(int), stream);
    hist_k<<<egrid, 256, 0, stream>>>(dst, cnt, n_edges);
    const int nb = (n_nodes + 2047) / 2048;
    scan_block_k<<<nb, 256, 0, stream>>>(cnt, offs, bsum, n_nodes);
    scan_bsum_k<<<1, 256, 0, stream>>>(bsum, nb);
    scan_add_k<<<nb, 256, 0, stream>>>(offs, cur, bsum, n_nodes);
    fill_seg_k<<<seg_grid, 256, 0, stream>>>(src, dst, cur, eidx, n_edges, segN);

    // ---- layer 1 ----
    gather_agg_k<64><<<(n_nodes + 31) / 32, 256, 0, stream>>>(
        xb, offs, cnt, eidx, A, n_nodes);
    mlp_mfma_k<64, 128, true, true><<<mlp_grid, 256, 0, stream>>>(
        A, WT1a, b1a, WT1b, b1b, h, n_nodes);

    // ---- layer 2 ----
    gather_agg_k<128><<<(n_nodes + 15) / 16, 256, 0, stream>>>(
        h, offs, cnt, eidx, A, n_nodes);
    mlp_mfma_k<128, 64, false, false><<<mlp_grid, 256, 0, stream>>>(
        A, WT2a, b2a, WT2b, b2b, d_out, n_nodes);
}